// Round 7
// baseline (5873.174 us; speedup 1.0000x reference)
//
#include <hip/hip_runtime.h>
#include <hip/hip_bf16.h>
#include <math.h>

// Problem constants
#define V_    8000
#define E_    150
#define LD_   50
#define H_    512
#define B_    100
#define T_    50
#define D0_   200   // E_+LD_
#define BT_   5000  // B_*T_
#define NV_   8000

typedef __attribute__((ext_vector_type(8))) short short8v;
typedef __attribute__((ext_vector_type(4))) float f32x4;

__device__ __forceinline__ float sigmoidf_(float x) { return 1.0f / (1.0f + expf(-x)); }
__device__ __forceinline__ unsigned short f2b(float x) {
    __hip_bfloat16 b = __float2bfloat16(x);
    return *(unsigned short*)&b;
}

// ---------------- row L2-normalize
__global__ __launch_bounds__(256) void norm_rows(const float* __restrict__ in,
                                                 float* __restrict__ out, int R, int C) {
    int row = blockIdx.x;
    if (row >= R) return;
    int tid = threadIdx.x;
    float v = (tid < C) ? in[(size_t)row * C + tid] : 0.f;
    __shared__ float red[256];
    red[tid] = v * v;
    __syncthreads();
    for (int s = 128; s > 0; s >>= 1) {
        if (tid < s) red[tid] += red[tid + s];
        __syncthreads();
    }
    float scale = rsqrtf(fmaxf(red[0], 1e-12f));
    if (tid < C) out[(size_t)row * C + tid] = v * scale;
}

// ---------------- build xs [m=t*100+b][D0] row-major
__global__ void build_xs(const int* __restrict__ inp, const int* __restrict__ langs,
                         const float* __restrict__ nemb, const float* __restrict__ nlang,
                         float* __restrict__ xs) {
    int idx = blockIdx.x * 256 + threadIdx.x;
    if (idx >= T_ * B_ * D0_) return;
    int t = idx / (B_ * D0_);
    int rem = idx % (B_ * D0_);
    int b = rem / D0_;
    int e = rem % D0_;
    float v;
    if (e < E_) v = nemb[(size_t)inp[b * T_ + t] * E_ + e];
    else        v = nlang[(size_t)langs[b] * LD_ + (e - E_)];
    xs[idx] = v;
}

// ---------------- fp32 tiled GEMM + bias: C[M,N] = A[M,K]@B[K,N](ldb) + bias
__global__ __launch_bounds__(256) void gemm_bias(const float* __restrict__ A,
                                                 const float* __restrict__ Bm,
                                                 const float* __restrict__ bias,
                                                 float* __restrict__ C,
                                                 int M, int N, int K, int ldb) {
    __shared__ __align__(16) float As[16][64];
    __shared__ __align__(16) float Bs[16][64];
    const int tid = threadIdx.x;
    const int tx = tid & 15, ty = tid >> 4;
    const int mBase = blockIdx.y * 64, nBase = blockIdx.x * 64;
    float acc[4][4] = {};
    for (int k0 = 0; k0 < K; k0 += 16) {
        int e = tid * 4;
#pragma unroll
        for (int q = 0; q < 4; ++q) {
            int ee = e + q;
            int r = ee >> 4, kk = ee & 15;
            int gr = mBase + r, gk = k0 + kk;
            As[kk][r] = (gr < M && gk < K) ? A[(size_t)gr * K + gk] : 0.f;
        }
        int bk = tid >> 4, bn = (tid & 15) * 4;
        int gk = k0 + bk;
        float4 bv = make_float4(0.f, 0.f, 0.f, 0.f);
        if (gk < K) bv = *(const float4*)(Bm + (size_t)gk * ldb + nBase + bn);
        *(float4*)&Bs[bk][bn] = bv;
        __syncthreads();
#pragma unroll
        for (int kk = 0; kk < 16; ++kk) {
            const float4 a4 = *(const float4*)&As[kk][ty * 4];
            const float4 b4 = *(const float4*)&Bs[kk][tx * 4];
            float a[4] = {a4.x, a4.y, a4.z, a4.w};
            float b[4] = {b4.x, b4.y, b4.z, b4.w};
#pragma unroll
            for (int i = 0; i < 4; ++i)
#pragma unroll
                for (int j = 0; j < 4; ++j) acc[i][j] += a[i] * b[j];
        }
        __syncthreads();
    }
#pragma unroll
    for (int i = 0; i < 4; ++i) {
        int gr = mBase + ty * 4 + i;
        if (gr < M) {
#pragma unroll
            for (int j = 0; j < 4; ++j) {
                int gc = nBase + tx * 4 + j;
                if (gc < N) C[(size_t)gr * N + gc] = acc[i][j] + bias[gc];
            }
        }
    }
}

// ---------------- pack fp32 weight [K][ldw] (rows k0off..) into bf16 MFMA B-frag layout:
// dst[((kt*NT + nt)*64 + lane)*8 + j] = bf16(W[k0off + kt*32 + (lane>>4)*8 + j][nt*16 + (lane&15)])
__global__ __launch_bounds__(256) void pack_frags(const float* __restrict__ W, int ldw,
                                                  int k0off, int KT, int NT,
                                                  unsigned short* __restrict__ dst) {
    int idx = blockIdx.x * 256 + threadIdx.x;
    if (idx >= KT * NT * 64) return;
    int lane = idx & 63;
    int tile = idx >> 6;
    int nt = tile % NT, kt = tile / NT;
    int n = nt * 16 + (lane & 15);
    int kb = k0off + kt * 32 + (lane >> 4) * 8;
    unsigned short o[8];
#pragma unroll
    for (int j = 0; j < 8; ++j) o[j] = f2b(W[(size_t)(kb + j) * ldw + n]);
    *(uint4*)(dst + (size_t)idx * 8) = *(const uint4*)o;
}

// ---------------- MFMA recurrence phase (proven simple loop, compiler-scheduled).
// K = KT*32; A k-tiles 0..15 from a0, 16..31 from a1. aoff = (lane&15)*520 + (lane>>4)*8.
template<int KT, int NTW>
__device__ __forceinline__ void mm_phase(const unsigned short* __restrict__ Wf, int NT,
                                         const unsigned short* a0, const unsigned short* a1,
                                         int w, int lane, int aoff, f32x4* acc) {
#pragma unroll 4
    for (int kt = 0; kt < KT; ++kt) {
        const unsigned short* src = (KT > 16 && kt >= 16) ? a1 : a0;
        int ktl = (KT > 16 && kt >= 16) ? kt - 16 : kt;
        short8v af = *(const short8v*)(src + aoff + ktl * 32);
        const unsigned short* wp = Wf + ((size_t)(kt * NT + w * NTW) * 64 + lane) * 8;
#pragma unroll
        for (int nt = 0; nt < NTW; ++nt) {
            short8v bf = *(const short8v*)(wp + (size_t)nt * 512);
            acc[nt] = __builtin_amdgcn_mfma_f32_16x16x32_bf16(af, bf, acc[nt], 0, 0, 0);
        }
    }
}

// ---------------- barrier-free recurrence: 13 blocks x 8 batch rows, 1024 threads (16 waves)
// 4x lower aggregate weight-stream demand than 50-block version; M=16 MFMA tile holds 8 rows.
// Rows 100..103 are padding: computed but never stored (guard rowb < 100).
__global__ __launch_bounds__(1024) void rnn_mfma(
    const float* __restrict__ Xg0, const float* __restrict__ Xc0,
    const unsigned short* __restrict__ Wg0f, const unsigned short* __restrict__ Wc0f,
    const unsigned short* __restrict__ Wg1f, const unsigned short* __restrict__ Wc1f,
    const float* __restrict__ bg1, const float* __restrict__ bc1,
    float* __restrict__ h1o) {
    __shared__ __align__(16) unsigned short h0b[16 * 520];
    __shared__ __align__(16) unsigned short h1b[16 * 520];
    __shared__ __align__(16) unsigned short rh0b[16 * 520];
    __shared__ __align__(16) unsigned short rh1b[16 * 520];
    __shared__ float h0f[8 * 512], h1f[8 * 512], u0f[8 * 512], u1f[8 * 512];
    const int tid = threadIdx.x;
    const int w = tid >> 6, lane = tid & 63;   // w in 0..15
    const int arow = lane & 15;
    const int hi = lane >> 4;                  // 0..3; epilogue uses lanes<32 (hi 0/1)
    const int aoff = arow * 520 + hi * 8;
    const int rb = blockIdx.x * 8;

    for (int i = tid; i < 16 * 520; i += 1024) { h0b[i] = 0; h1b[i] = 0; rh0b[i] = 0; rh1b[i] = 0; }
    for (int i = tid; i < 8 * 512; i += 1024) { h0f[i] = 0.f; h1f[i] = 0.f; }
    // hoist layer-1 biases (fixed cols per lane): A/C waves own 4 tiles, B/D own 2
    float bg1v[4], bc1v[2];
#pragma unroll
    for (int nt = 0; nt < 4; ++nt) bg1v[nt] = bg1[(w * 4 + nt) * 16 + arow];
#pragma unroll
    for (int nt = 0; nt < 2; ++nt) bc1v[nt] = bc1[(w * 2 + nt) * 16 + arow];
    __syncthreads();

    for (int t = 0; t < T_; ++t) {
        const int m0 = t * 100 + rb;          // first of 8 rows (may exceed valid range; reads
                                              // past Xg0/Xc0 rows stay inside d_ws, stores guarded)
        {   // phase A: gates0 = sigmoid(Xg0 + h0 @ Wg0h)  [N=1024, K=512]
            float xg[4][4];                   // [q][nt] for this lane's 4 rows
            if (lane < 32) {
#pragma unroll
                for (int nt = 0; nt < 4; ++nt) {
                    int col = (w * 4 + nt) * 16 + arow;
#pragma unroll
                    for (int q = 0; q < 4; ++q)
                        xg[q][nt] = Xg0[(size_t)(m0 + hi * 4 + q) * 1024 + col];
                }
            }
            f32x4 acc[4];
#pragma unroll
            for (int nt = 0; nt < 4; ++nt) acc[nt] = (f32x4){0.f, 0.f, 0.f, 0.f};
            mm_phase<16, 4>(Wg0f, 64, h0b, h0b, w, lane, aoff, acc);
            if (lane < 32) {
#pragma unroll
                for (int nt = 0; nt < 4; ++nt) {
                    int col = (w * 4 + nt) * 16 + arow;
#pragma unroll
                    for (int q = 0; q < 4; ++q) {
                        int rowl = hi * 4 + q;
                        float s = sigmoidf_(acc[nt][q] + xg[q][nt]);
                        if (col < 512) rh0b[rowl * 520 + col] = f2b(s * h0f[rowl * 512 + col]);
                        else           u0f[rowl * 512 + col - 512] = s;
                    }
                }
            }
        }
        __syncthreads();
        {   // phase B: h0 = u*h0 + (1-u)*tanh(Xc0 + rh0 @ Wc0h)  [N=512, K=512]
            float xc[4][2];
            if (lane < 32) {
#pragma unroll
                for (int nt = 0; nt < 2; ++nt) {
                    int col = (w * 2 + nt) * 16 + arow;
#pragma unroll
                    for (int q = 0; q < 4; ++q)
                        xc[q][nt] = Xc0[(size_t)(m0 + hi * 4 + q) * 512 + col];
                }
            }
            f32x4 acc[2];
#pragma unroll
            for (int nt = 0; nt < 2; ++nt) acc[nt] = (f32x4){0.f, 0.f, 0.f, 0.f};
            mm_phase<16, 2>(Wc0f, 32, rh0b, rh0b, w, lane, aoff, acc);
            if (lane < 32) {
#pragma unroll
                for (int nt = 0; nt < 2; ++nt) {
                    int col = (w * 2 + nt) * 16 + arow;
#pragma unroll
                    for (int q = 0; q < 4; ++q) {
                        int rowl = hi * 4 + q;
                        float c = tanhf(acc[nt][q] + xc[q][nt]);
                        float u = u0f[rowl * 512 + col];
                        float hn = u * h0f[rowl * 512 + col] + (1.f - u) * c;
                        h0f[rowl * 512 + col] = hn;
                        h0b[rowl * 520 + col] = f2b(hn);
                    }
                }
            }
        }
        __syncthreads();
        {   // phase C: gates1 = sigmoid(bg1 + [h0,h1] @ Wg1)  [N=1024, K=1024]
            f32x4 acc[4];
#pragma unroll
            for (int nt = 0; nt < 4; ++nt) acc[nt] = (f32x4){0.f, 0.f, 0.f, 0.f};
            mm_phase<32, 4>(Wg1f, 64, h0b, h1b, w, lane, aoff, acc);
            if (lane < 32) {
#pragma unroll
                for (int nt = 0; nt < 4; ++nt) {
                    int col = (w * 4 + nt) * 16 + arow;
#pragma unroll
                    for (int q = 0; q < 4; ++q) {
                        int rowl = hi * 4 + q;
                        float s = sigmoidf_(acc[nt][q] + bg1v[nt]);
                        if (col < 512) rh1b[rowl * 520 + col] = f2b(s * h1f[rowl * 512 + col]);
                        else           u1f[rowl * 512 + col - 512] = s;
                    }
                }
            }
        }
        __syncthreads();
        {   // phase D: h1 = u1*h1 + (1-u1)*tanh(bc1 + [h0, rh1] @ Wc1)  [N=512, K=1024]
            f32x4 acc[2];
#pragma unroll
            for (int nt = 0; nt < 2; ++nt) acc[nt] = (f32x4){0.f, 0.f, 0.f, 0.f};
            mm_phase<32, 2>(Wc1f, 32, h0b, rh1b, w, lane, aoff, acc);
            if (lane < 32) {
#pragma unroll
                for (int nt = 0; nt < 2; ++nt) {
                    int col = (w * 2 + nt) * 16 + arow;
#pragma unroll
                    for (int q = 0; q < 4; ++q) {
                        int rowl = hi * 4 + q;
                        int rowb = rb + rowl;
                        float c = tanhf(acc[nt][q] + bc1v[nt]);
                        float u = u1f[rowl * 512 + col];
                        float hn = u * h1f[rowl * 512 + col] + (1.f - u) * c;
                        h1f[rowl * 512 + col] = hn;
                        h1b[rowl * 520 + col] = f2b(hn);
                        if (rowb < 100) h1o[(size_t)(t * 100 + rowb) * 512 + col] = hn;
                    }
                }
            }
        }
        __syncthreads();
    }
}

// ---------------- fused softmax GEMM + per-tile LSE partials + target-logit pick
// A = h1o [BT][512] row-major, B = sw [512][8000]
__global__ __launch_bounds__(256) void lse_gemm(const float* __restrict__ A,
                                                const float* __restrict__ Bw,
                                                const float* __restrict__ bias,
                                                const int* __restrict__ tgt,
                                                float* __restrict__ zt,
                                                float* __restrict__ parts, int M) {
    __shared__ __align__(16) float As[16][64];
    __shared__ __align__(16) float Bs[16][64];
    __shared__ float red[64][17];
    __shared__ float rowm[64];
    const int tid = threadIdx.x;
    const int tx = tid & 15, ty = tid >> 4;
    const int mBase = blockIdx.y * 64, nBase = blockIdx.x * 64;
    float acc[4][4] = {};
    for (int k0 = 0; k0 < 512; k0 += 16) {
        int r = tid >> 2;
        int ak = (tid & 3) * 4;
        float4 av = make_float4(0.f, 0.f, 0.f, 0.f);
        if (mBase + r < M) av = *(const float4*)(A + (size_t)(mBase + r) * 512 + k0 + ak);
        As[ak][r] = av.x; As[ak + 1][r] = av.y; As[ak + 2][r] = av.z; As[ak + 3][r] = av.w;
        int bk = tid >> 4, bn = (tid & 15) * 4;
        float4 bv = *(const float4*)(Bw + (size_t)(k0 + bk) * NV_ + nBase + bn);
        *(float4*)&Bs[bk][bn] = bv;
        __syncthreads();
#pragma unroll
        for (int kk = 0; kk < 16; ++kk) {
            const float4 a4 = *(const float4*)&As[kk][ty * 4];
            const float4 b4 = *(const float4*)&Bs[kk][tx * 4];
            float a[4] = {a4.x, a4.y, a4.z, a4.w};
            float b[4] = {b4.x, b4.y, b4.z, b4.w};
#pragma unroll
            for (int i = 0; i < 4; ++i)
#pragma unroll
                for (int j = 0; j < 4; ++j) acc[i][j] += a[i] * b[j];
        }
        __syncthreads();
    }
#pragma unroll
    for (int j = 0; j < 4; ++j) {
        float bb = bias[nBase + tx * 4 + j];
#pragma unroll
        for (int i = 0; i < 4; ++i) acc[i][j] += bb;
    }
    // target-logit pick: row m = t*100+b pairs with tgt[b*50+t] = tgt[(m%100)*50 + m/100]
#pragma unroll
    for (int i = 0; i < 4; ++i) {
        int gr = mBase + ty * 4 + i;
        if (gr < M) {
            int tg = tgt[(gr % 100) * 50 + gr / 100];
            int lj = tg - nBase - tx * 4;
            if (lj == 0) zt[gr] = acc[i][0];
            else if (lj == 1) zt[gr] = acc[i][1];
            else if (lj == 2) zt[gr] = acc[i][2];
            else if (lj == 3) zt[gr] = acc[i][3];
        }
    }
#pragma unroll
    for (int i = 0; i < 4; ++i) {
        float lm = fmaxf(fmaxf(acc[i][0], acc[i][1]), fmaxf(acc[i][2], acc[i][3]));
        red[ty * 4 + i][tx] = lm;
    }
    __syncthreads();
    if (tid < 64) {
        float m = red[tid][0];
#pragma unroll
        for (int c = 1; c < 16; ++c) m = fmaxf(m, red[tid][c]);
        rowm[tid] = m;
    }
    __syncthreads();
#pragma unroll
    for (int i = 0; i < 4; ++i) {
        float m = rowm[ty * 4 + i];
        float ls = expf(acc[i][0] - m) + expf(acc[i][1] - m) + expf(acc[i][2] - m) + expf(acc[i][3] - m);
        red[ty * 4 + i][tx] = ls;
    }
    __syncthreads();
    if (tid < 64) {
        float s = 0.f;
#pragma unroll
        for (int c = 0; c < 16; ++c) s += red[tid][c];
        int gr = mBase + tid;
        if (gr < M) {
            parts[(size_t)gr * 250 + blockIdx.x * 2 + 0] = rowm[tid];
            parts[(size_t)gr * 250 + blockIdx.x * 2 + 1] = s;
        }
    }
}

// ---------------- merge partials -> NLL -> block sums
__global__ __launch_bounds__(128) void final_nll(const float* __restrict__ parts,
                                                 const float* __restrict__ zt,
                                                 float* __restrict__ bsum) {
    int i = blockIdx.x * 128 + threadIdx.x;
    float nll = 0.f;
    if (i < BT_) {
        const float* p = parts + (size_t)i * 250;
        float M = p[0];
        for (int j = 1; j < 125; ++j) M = fmaxf(M, p[2 * j]);
        float S = 0.f;
        for (int j = 0; j < 125; ++j) S += p[2 * j + 1] * expf(p[2 * j] - M);
        nll = M + logf(S) - zt[i];
    }
    __shared__ float red[128];
    red[threadIdx.x] = nll;
    __syncthreads();
    for (int s = 64; s > 0; s >>= 1) {
        if (threadIdx.x < s) red[threadIdx.x] += red[threadIdx.x + s];
        __syncthreads();
    }
    if (threadIdx.x == 0) bsum[blockIdx.x] = red[0];
}

__global__ __launch_bounds__(64) void final_sum(const float* __restrict__ bsum,
                                                float* __restrict__ out) {
    int tid = threadIdx.x;
    float v = (tid < 40) ? bsum[tid] : 0.f;
    for (int off = 32; off > 0; off >>= 1) v += __shfl_down(v, off);
    if (tid == 0) out[0] = v / 5000.0f;
}

extern "C" void kernel_launch(void* const* d_in, const int* in_sizes, int n_in,
                              void* d_out, int out_size, void* d_ws, size_t ws_size,
                              hipStream_t stream) {
    const int*   inp   = (const int*)d_in[0];
    const int*   langs = (const int*)d_in[1];
    const int*   tgt   = (const int*)d_in[2];
    const float* emb   = (const float*)d_in[3];
    const float* lemb  = (const float*)d_in[4];
    const float* Wg0   = (const float*)d_in[5];
    const float* bg0   = (const float*)d_in[6];
    const float* Wc0   = (const float*)d_in[7];
    const float* bc0   = (const float*)d_in[8];
    const float* Wg1   = (const float*)d_in[9];
    const float* bg1   = (const float*)d_in[10];
    const float* Wc1   = (const float*)d_in[11];
    const float* bc1   = (const float*)d_in[12];
    const float* sw    = (const float*)d_in[13];
    const float* sb    = (const float*)d_in[14];
    float* out = (float*)d_out;

    // workspace layout (floats), total 12,440,512 floats = 49.76 MB
    float* w = (float*)d_ws;
    // region A [0 .. 1,200,000): nemb, later aliased by packed weight frags (1,179,648 fl)
    float* nemb  = w;
    unsigned short* Wg0f = (unsigned short*)w;                 //   524,288 u16
    unsigned short* Wg1f = Wg0f + 524288;                      // 1,048,576 u16
    unsigned short* Wc0f = Wg1f + 1048576;                     //   262,144 u16
    unsigned short* Wc1f = Wc0f + 262144;                      //   524,288 u16 (ends 2,359,296 u16)
    float* nlang = w + 1200000;             // 512
    float* xs    = w + 1200512;             // 1,000,000 (dead after gemms)
    float* Xg0   = w + 2200512;             // 5,120,000, later aliased by parts/zt/bsum
    float* parts = w + 2200512;             // 1,250,000
    float* ztb   = w + 2200512 + 1250000;   // 5,000
    float* bsum  = w + 2200512 + 1255000;   // 64
    float* Xc0   = w + 7320512;             // 2,560,000
    float* h1o   = w + 9880512;             // 2,560,000 (ends 12,440,512)

    norm_rows<<<V_, 256, 0, stream>>>(emb, nemb, V_, E_);
    norm_rows<<<10, 256, 0, stream>>>(lemb, nlang, 10, LD_);
    build_xs<<<(T_ * B_ * D0_ + 255) / 256, 256, 0, stream>>>(inp, langs, nemb, nlang, xs);
    // pack weights into bf16 B-fragment layout (overwrites nemb region; after build_xs)
    pack_frags<<<256, 256, 0, stream>>>(Wg0, 1024, D0_, 16, 64, Wg0f);   // h-part rows 200..711
    pack_frags<<<512, 256, 0, stream>>>(Wg1, 1024, 0,   32, 64, Wg1f);
    pack_frags<<<128, 256, 0, stream>>>(Wc0,  512, D0_, 16, 32, Wc0f);
    pack_frags<<<256, 256, 0, stream>>>(Wc1,  512, 0,   32, 32, Wc1f);
    // input-side projections (x-part of layer-0 GRU), row-major [m][N]
    gemm_bias<<<dim3(16, 79), 256, 0, stream>>>(xs, Wg0, bg0, Xg0, BT_, 1024, D0_, 1024);
    gemm_bias<<<dim3(8, 79), 256, 0, stream>>>(xs, Wc0, bc0, Xc0, BT_, 512, D0_, 512);
    // barrier-free MFMA recurrence: 13 blocks x 8 batch rows (rows 100..103 padded/guarded)
    rnn_mfma<<<13, 1024, 0, stream>>>(Xg0, Xc0, Wg0f, Wc0f, Wg1f, Wc1f, bg1, bc1, h1o);
    // fused softmax GEMM + LSE partials + target pick
    lse_gemm<<<dim3(125, 79), 256, 0, stream>>>(h1o, sw, sb, tgt, ztb, parts, BT_);
    final_nll<<<40, 128, 0, stream>>>(parts, ztb, bsum);
    final_sum<<<1, 64, 0, stream>>>(bsum, out);
}

// Round 8
// 2484.803 us; speedup vs baseline: 2.3636x; 2.3636x over previous
//
#include <hip/hip_runtime.h>
#include <hip/hip_bf16.h>
#include <math.h>

// Problem constants
#define V_    8000
#define E_    150
#define LD_   50
#define H_    512
#define B_    100
#define T_    50
#define D0_   200   // E_+LD_
#define BT_   5000  // B_*T_
#define NV_   8000

typedef __attribute__((ext_vector_type(8))) short short8v;
typedef __attribute__((ext_vector_type(4))) float f32x4;

__device__ __forceinline__ float sigmoidf_(float x) { return 1.0f / (1.0f + expf(-x)); }
__device__ __forceinline__ unsigned short f2b(float x) {
    __hip_bfloat16 b = __float2bfloat16(x);
    return *(unsigned short*)&b;
}

// ---------------- row L2-normalize
__global__ __launch_bounds__(256) void norm_rows(const float* __restrict__ in,
                                                 float* __restrict__ out, int R, int C) {
    int row = blockIdx.x;
    if (row >= R) return;
    int tid = threadIdx.x;
    float v = (tid < C) ? in[(size_t)row * C + tid] : 0.f;
    __shared__ float red[256];
    red[tid] = v * v;
    __syncthreads();
    for (int s = 128; s > 0; s >>= 1) {
        if (tid < s) red[tid] += red[tid + s];
        __syncthreads();
    }
    float scale = rsqrtf(fmaxf(red[0], 1e-12f));
    if (tid < C) out[(size_t)row * C + tid] = v * scale;
}

// ---------------- build xs [m=t*100+b][D0] row-major
__global__ void build_xs(const int* __restrict__ inp, const int* __restrict__ langs,
                         const float* __restrict__ nemb, const float* __restrict__ nlang,
                         float* __restrict__ xs) {
    int idx = blockIdx.x * 256 + threadIdx.x;
    if (idx >= T_ * B_ * D0_) return;
    int t = idx / (B_ * D0_);
    int rem = idx % (B_ * D0_);
    int b = rem / D0_;
    int e = rem % D0_;
    float v;
    if (e < E_) v = nemb[(size_t)inp[b * T_ + t] * E_ + e];
    else        v = nlang[(size_t)langs[b] * LD_ + (e - E_)];
    xs[idx] = v;
}

// ---------------- fp32 tiled GEMM + bias: C[M,N] = A[M,K]@B[K,N](ldb) + bias
__global__ __launch_bounds__(256) void gemm_bias(const float* __restrict__ A,
                                                 const float* __restrict__ Bm,
                                                 const float* __restrict__ bias,
                                                 float* __restrict__ C,
                                                 int M, int N, int K, int ldb) {
    __shared__ __align__(16) float As[16][64];
    __shared__ __align__(16) float Bs[16][64];
    const int tid = threadIdx.x;
    const int tx = tid & 15, ty = tid >> 4;
    const int mBase = blockIdx.y * 64, nBase = blockIdx.x * 64;
    float acc[4][4] = {};
    for (int k0 = 0; k0 < K; k0 += 16) {
        int e = tid * 4;
#pragma unroll
        for (int q = 0; q < 4; ++q) {
            int ee = e + q;
            int r = ee >> 4, kk = ee & 15;
            int gr = mBase + r, gk = k0 + kk;
            As[kk][r] = (gr < M && gk < K) ? A[(size_t)gr * K + gk] : 0.f;
        }
        int bk = tid >> 4, bn = (tid & 15) * 4;
        int gk = k0 + bk;
        float4 bv = make_float4(0.f, 0.f, 0.f, 0.f);
        if (gk < K) bv = *(const float4*)(Bm + (size_t)gk * ldb + nBase + bn);
        *(float4*)&Bs[bk][bn] = bv;
        __syncthreads();
#pragma unroll
        for (int kk = 0; kk < 16; ++kk) {
            const float4 a4 = *(const float4*)&As[kk][ty * 4];
            const float4 b4 = *(const float4*)&Bs[kk][tx * 4];
            float a[4] = {a4.x, a4.y, a4.z, a4.w};
            float b[4] = {b4.x, b4.y, b4.z, b4.w};
#pragma unroll
            for (int i = 0; i < 4; ++i)
#pragma unroll
                for (int j = 0; j < 4; ++j) acc[i][j] += a[i] * b[j];
        }
        __syncthreads();
    }
#pragma unroll
    for (int i = 0; i < 4; ++i) {
        int gr = mBase + ty * 4 + i;
        if (gr < M) {
#pragma unroll
            for (int j = 0; j < 4; ++j) {
                int gc = nBase + tx * 4 + j;
                if (gc < N) C[(size_t)gr * N + gc] = acc[i][j] + bias[gc];
            }
        }
    }
}

// ---------------- pack fp32 weight [K][ldw] (rows k0off..) into bf16 MFMA B-frag layout:
// dst[((kt*NT + nt)*64 + lane)*8 + j] = bf16(W[k0off + kt*32 + (lane>>4)*8 + j][nt*16 + (lane&15)])
__global__ __launch_bounds__(256) void pack_frags(const float* __restrict__ W, int ldw,
                                                  int k0off, int KT, int NT,
                                                  unsigned short* __restrict__ dst) {
    int idx = blockIdx.x * 256 + threadIdx.x;
    if (idx >= KT * NT * 64) return;
    int lane = idx & 63;
    int tile = idx >> 6;
    int nt = tile % NT, kt = tile / NT;
    int n = nt * 16 + (lane & 15);
    int kb = k0off + kt * 32 + (lane >> 4) * 8;
    unsigned short o[8];
#pragma unroll
    for (int j = 0; j < 8; ++j) o[j] = f2b(W[(size_t)(kb + j) * ldw + n]);
    *(uint4*)(dst + (size_t)idx * 8) = *(const uint4*)o;
}

// ---------------- MFMA recurrence phase (round-3 proven form, compiler-scheduled).
// K = 16*32 = 512. aoff = (lane&15)*520 + (lane>>4)*8.
template<int NTW>
__device__ __forceinline__ void mm_phase(const unsigned short* __restrict__ Wf, int NT,
                                         const unsigned short* a0,
                                         int w, int lane, int aoff, f32x4* acc) {
#pragma unroll 2
    for (int kt = 0; kt < 16; ++kt) {
        short8v af = *(const short8v*)(a0 + aoff + kt * 32);
        const unsigned short* wp = Wf + ((size_t)(kt * NT + w * NTW) * 64 + lane) * 8;
#pragma unroll
        for (int nt = 0; nt < NTW; ++nt) {
            short8v bf = *(const short8v*)(wp + (size_t)nt * 512);
            acc[nt] = __builtin_amdgcn_mfma_f32_16x16x32_bf16(af, bf, acc[nt], 0, 0, 0);
        }
    }
}

// ---------------- one-layer GRU pass: 50 blocks x 2 batch rows, 512 threads (8 waves)
// gates = sigmoid(Xg[m] + h @ Wgf); h = u*h + (1-u)*tanh(Xc[m] + (r*h) @ Wcf)
// Weight set per step = 1.5 MB (L2-resident). Outputs: houtb (bf16) and/or houtf (fp32).
__global__ __launch_bounds__(512) void rnn_pass(
    const float* __restrict__ Xg, const float* __restrict__ Xc,
    const unsigned short* __restrict__ Wgf, const unsigned short* __restrict__ Wcf,
    unsigned short* __restrict__ houtb, float* __restrict__ houtf) {
    __shared__ __align__(16) unsigned short hb[16 * 520];
    __shared__ __align__(16) unsigned short rhb[16 * 520];
    __shared__ float hf[2 * 512], uf[2 * 512];
    const int tid = threadIdx.x;
    const int w = tid >> 6, lane = tid & 63;
    const int arow = lane & 15;
    const int aoff = arow * 520 + (lane >> 4) * 8;
    const int rb = blockIdx.x * 2;

    for (int i = tid; i < 16 * 520; i += 512) { hb[i] = 0; rhb[i] = 0; }
    for (int i = tid; i < 2 * 512; i += 512) hf[i] = 0.f;
    __syncthreads();

    for (int t = 0; t < T_; ++t) {
        const int m0 = t * 100 + rb, m1 = m0 + 1;
        {   // phase A: gates [N=1024, K=512]
            f32x4 acc[8];
#pragma unroll
            for (int nt = 0; nt < 8; ++nt) acc[nt] = (f32x4){0.f, 0.f, 0.f, 0.f};
            mm_phase<8>(Wgf, 64, hb, w, lane, aoff, acc);
            if (lane < 16) {
#pragma unroll
                for (int nt = 0; nt < 8; ++nt) {
                    int col = (w * 8 + nt) * 16 + arow;
                    float s0 = sigmoidf_(acc[nt][0] + Xg[(size_t)m0 * 1024 + col]);
                    float s1 = sigmoidf_(acc[nt][1] + Xg[(size_t)m1 * 1024 + col]);
                    if (col < 512) {
                        rhb[col]       = f2b(s0 * hf[col]);
                        rhb[520 + col] = f2b(s1 * hf[512 + col]);
                    } else {
                        uf[col - 512] = s0;
                        uf[col]       = s1;
                    }
                }
            }
        }
        __syncthreads();
        {   // phase B: candidate + h update [N=512, K=512]
            f32x4 acc[4];
#pragma unroll
            for (int nt = 0; nt < 4; ++nt) acc[nt] = (f32x4){0.f, 0.f, 0.f, 0.f};
            mm_phase<4>(Wcf, 32, rhb, w, lane, aoff, acc);
            if (lane < 16) {
#pragma unroll
                for (int nt = 0; nt < 4; ++nt) {
                    int col = (w * 4 + nt) * 16 + arow;
                    float c0 = tanhf(acc[nt][0] + Xc[(size_t)m0 * 512 + col]);
                    float c1 = tanhf(acc[nt][1] + Xc[(size_t)m1 * 512 + col]);
                    float uA = uf[col], uB = uf[512 + col];
                    float hA = uA * hf[col] + (1.f - uA) * c0;
                    float hB = uB * hf[512 + col] + (1.f - uB) * c1;
                    hf[col] = hA; hf[512 + col] = hB;
                    unsigned short bA = f2b(hA), bB = f2b(hB);
                    hb[col] = bA; hb[520 + col] = bB;
                    if (houtb) {
                        houtb[(size_t)m0 * 512 + col] = bA;
                        houtb[(size_t)m1 * 512 + col] = bB;
                    }
                    if (houtf) {
                        houtf[(size_t)m0 * 512 + col] = hA;
                        houtf[(size_t)m1 * 512 + col] = hB;
                    }
                }
            }
        }
        __syncthreads();
    }
}

// ---------------- batched MFMA x-projection GEMM: C[M][N] = Abf[M][512] @ Wf + bias
// One 16-row M-tile per block, 4 waves x NTW n-tiles. N = NTW*4*16.
template<int NTW>
__global__ __launch_bounds__(256) void xproj_mfma(const unsigned short* __restrict__ Abf,
                                                  const unsigned short* __restrict__ Wf,
                                                  const float* __restrict__ bias,
                                                  float* __restrict__ C, int M) {
    const int NT = NTW * 4;
    const int N = NT * 16;
    const int tid = threadIdx.x;
    const int w = tid >> 6, lane = tid & 63;
    const int arow = lane & 15, hi = lane >> 4;
    const int mbase = blockIdx.x * 16;
    int ga = mbase + arow; if (ga >= M) ga = M - 1;      // clamp reads; stores guarded
    const unsigned short* ap = Abf + (size_t)ga * 512 + hi * 8;
    f32x4 acc[NTW];
#pragma unroll
    for (int nt = 0; nt < NTW; ++nt) acc[nt] = (f32x4){0.f, 0.f, 0.f, 0.f};
#pragma unroll 2
    for (int kt = 0; kt < 16; ++kt) {
        short8v af = *(const short8v*)(ap + kt * 32);
        const unsigned short* wp = Wf + ((size_t)(kt * NT + w * NTW) * 64 + lane) * 8;
#pragma unroll
        for (int nt = 0; nt < NTW; ++nt) {
            short8v bf = *(const short8v*)(wp + (size_t)nt * 512);
            acc[nt] = __builtin_amdgcn_mfma_f32_16x16x32_bf16(af, bf, acc[nt], 0, 0, 0);
        }
    }
    // C layout: row = hi*4+q, col = tile*16 + arow
#pragma unroll
    for (int nt = 0; nt < NTW; ++nt) {
        int col = (w * NTW + nt) * 16 + arow;
        float bb = bias[col];
#pragma unroll
        for (int q = 0; q < 4; ++q) {
            int gm = mbase + hi * 4 + q;
            if (gm < M) C[(size_t)gm * N + col] = acc[nt][q] + bb;
        }
    }
}

// ---------------- fused softmax GEMM + per-tile LSE partials + target-logit pick
// A = h1o [BT][512] row-major, B = sw [512][8000]
__global__ __launch_bounds__(256) void lse_gemm(const float* __restrict__ A,
                                                const float* __restrict__ Bw,
                                                const float* __restrict__ bias,
                                                const int* __restrict__ tgt,
                                                float* __restrict__ zt,
                                                float* __restrict__ parts, int M) {
    __shared__ __align__(16) float As[16][64];
    __shared__ __align__(16) float Bs[16][64];
    __shared__ float red[64][17];
    __shared__ float rowm[64];
    const int tid = threadIdx.x;
    const int tx = tid & 15, ty = tid >> 4;
    const int mBase = blockIdx.y * 64, nBase = blockIdx.x * 64;
    float acc[4][4] = {};
    for (int k0 = 0; k0 < 512; k0 += 16) {
        int r = tid >> 2;
        int ak = (tid & 3) * 4;
        float4 av = make_float4(0.f, 0.f, 0.f, 0.f);
        if (mBase + r < M) av = *(const float4*)(A + (size_t)(mBase + r) * 512 + k0 + ak);
        As[ak][r] = av.x; As[ak + 1][r] = av.y; As[ak + 2][r] = av.z; As[ak + 3][r] = av.w;
        int bk = tid >> 4, bn = (tid & 15) * 4;
        float4 bv = *(const float4*)(Bw + (size_t)(k0 + bk) * NV_ + nBase + bn);
        *(float4*)&Bs[bk][bn] = bv;
        __syncthreads();
#pragma unroll
        for (int kk = 0; kk < 16; ++kk) {
            const float4 a4 = *(const float4*)&As[kk][ty * 4];
            const float4 b4 = *(const float4*)&Bs[kk][tx * 4];
            float a[4] = {a4.x, a4.y, a4.z, a4.w};
            float b[4] = {b4.x, b4.y, b4.z, b4.w};
#pragma unroll
            for (int i = 0; i < 4; ++i)
#pragma unroll
                for (int j = 0; j < 4; ++j) acc[i][j] += a[i] * b[j];
        }
        __syncthreads();
    }
#pragma unroll
    for (int j = 0; j < 4; ++j) {
        float bb = bias[nBase + tx * 4 + j];
#pragma unroll
        for (int i = 0; i < 4; ++i) acc[i][j] += bb;
    }
    // target-logit pick: row m = t*100+b pairs with tgt[b*50+t] = tgt[(m%100)*50 + m/100]
#pragma unroll
    for (int i = 0; i < 4; ++i) {
        int gr = mBase + ty * 4 + i;
        if (gr < M) {
            int tg = tgt[(gr % 100) * 50 + gr / 100];
            int lj = tg - nBase - tx * 4;
            if (lj == 0) zt[gr] = acc[i][0];
            else if (lj == 1) zt[gr] = acc[i][1];
            else if (lj == 2) zt[gr] = acc[i][2];
            else if (lj == 3) zt[gr] = acc[i][3];
        }
    }
#pragma unroll
    for (int i = 0; i < 4; ++i) {
        float lm = fmaxf(fmaxf(acc[i][0], acc[i][1]), fmaxf(acc[i][2], acc[i][3]));
        red[ty * 4 + i][tx] = lm;
    }
    __syncthreads();
    if (tid < 64) {
        float m = red[tid][0];
#pragma unroll
        for (int c = 1; c < 16; ++c) m = fmaxf(m, red[tid][c]);
        rowm[tid] = m;
    }
    __syncthreads();
#pragma unroll
    for (int i = 0; i < 4; ++i) {
        float m = rowm[ty * 4 + i];
        float ls = expf(acc[i][0] - m) + expf(acc[i][1] - m) + expf(acc[i][2] - m) + expf(acc[i][3] - m);
        red[ty * 4 + i][tx] = ls;
    }
    __syncthreads();
    if (tid < 64) {
        float s = 0.f;
#pragma unroll
        for (int c = 0; c < 16; ++c) s += red[tid][c];
        int gr = mBase + tid;
        if (gr < M) {
            parts[(size_t)gr * 250 + blockIdx.x * 2 + 0] = rowm[tid];
            parts[(size_t)gr * 250 + blockIdx.x * 2 + 1] = s;
        }
    }
}

// ---------------- merge partials -> NLL -> block sums
__global__ __launch_bounds__(128) void final_nll(const float* __restrict__ parts,
                                                 const float* __restrict__ zt,
                                                 float* __restrict__ bsum) {
    int i = blockIdx.x * 128 + threadIdx.x;
    float nll = 0.f;
    if (i < BT_) {
        const float* p = parts + (size_t)i * 250;
        float M = p[0];
        for (int j = 1; j < 125; ++j) M = fmaxf(M, p[2 * j]);
        float S = 0.f;
        for (int j = 0; j < 125; ++j) S += p[2 * j + 1] * expf(p[2 * j] - M);
        nll = M + logf(S) - zt[i];
    }
    __shared__ float red[128];
    red[threadIdx.x] = nll;
    __syncthreads();
    for (int s = 64; s > 0; s >>= 1) {
        if (threadIdx.x < s) red[threadIdx.x] += red[threadIdx.x + s];
        __syncthreads();
    }
    if (threadIdx.x == 0) bsum[blockIdx.x] = red[0];
}

__global__ __launch_bounds__(64) void final_sum(const float* __restrict__ bsum,
                                                float* __restrict__ out) {
    int tid = threadIdx.x;
    float v = (tid < 40) ? bsum[tid] : 0.f;
    for (int off = 32; off > 0; off >>= 1) v += __shfl_down(v, off);
    if (tid == 0) out[0] = v / 5000.0f;
}

extern "C" void kernel_launch(void* const* d_in, const int* in_sizes, int n_in,
                              void* d_out, int out_size, void* d_ws, size_t ws_size,
                              hipStream_t stream) {
    const int*   inp   = (const int*)d_in[0];
    const int*   langs = (const int*)d_in[1];
    const int*   tgt   = (const int*)d_in[2];
    const float* emb   = (const float*)d_in[3];
    const float* lemb  = (const float*)d_in[4];
    const float* Wg0   = (const float*)d_in[5];
    const float* bg0   = (const float*)d_in[6];
    const float* Wc0   = (const float*)d_in[7];
    const float* bc0   = (const float*)d_in[8];
    const float* Wg1   = (const float*)d_in[9];
    const float* bg1   = (const float*)d_in[10];
    const float* Wc1   = (const float*)d_in[11];
    const float* bc1   = (const float*)d_in[12];
    const float* sw    = (const float*)d_in[13];
    const float* sb    = (const float*)d_in[14];
    float* out = (float*)d_out;

    // workspace layout (floats), total 12,440,512 floats = 49.76 MB
    float* w = (float*)d_ws;
    // region A [0 .. 1,200,000): nemb, later aliased by packed weight frags (2,359,296 u16)
    float* nemb  = w;
    unsigned short* Wg0f  = (unsigned short*)w;                //   524,288 u16
    unsigned short* Wc0f  = Wg0f + 524288;                     //   262,144
    unsigned short* Wg1xf = Wc0f + 262144;                     //   524,288
    unsigned short* Wg1hf = Wg1xf + 524288;                    //   524,288
    unsigned short* Wc1xf = Wg1hf + 524288;                    //   262,144
    unsigned short* Wc1hf = Wc1xf + 262144;                    //   262,144 (ends 2,359,296 u16)
    float* nlang = w + 1200000;             // 512
    float* xs    = w + 1200512;             // 1,000,000 (dead after Xg0/Xc0 gemms)
    // region B: Xg0, then Xg1 (alias), then parts/zt/bsum (alias)
    float* Xg0   = w + 2200512;             // 5,120,000
    float* Xg1   = w + 2200512;             // 5,120,000 (alias; Xg0 dead after pass1)
    float* parts = w + 2200512;             // 1,250,000 (alias; Xg1 dead after pass2)
    float* ztb   = w + 2200512 + 1250000;   // 5,000
    float* bsum  = w + 2200512 + 1255000;   // 64
    // region C: Xc0 then Xc1 (alias)
    float* Xc0   = w + 7320512;             // 2,560,000
    float* Xc1   = w + 7320512;             // (alias; Xc0 dead after pass1)
    // region D: h0seq (bf16) then h1o fp32 (alias; h0seq dead after xproj)
    unsigned short* h0seq = (unsigned short*)(w + 9880512);    // 2,621,440 u16
    float* h1o   = w + 9880512;             // 2,560,000 fl (ends 12,440,512)

    norm_rows<<<V_, 256, 0, stream>>>(emb, nemb, V_, E_);
    norm_rows<<<10, 256, 0, stream>>>(lemb, nlang, 10, LD_);
    build_xs<<<(T_ * B_ * D0_ + 255) / 256, 256, 0, stream>>>(inp, langs, nemb, nlang, xs);
    // pack all weight slices to bf16 frag layout (overwrites nemb; after build_xs)
    pack_frags<<<256, 256, 0, stream>>>(Wg0, 1024, D0_, 16, 64, Wg0f);   // layer0 gate h-part
    pack_frags<<<128, 256, 0, stream>>>(Wc0,  512, D0_, 16, 32, Wc0f);   // layer0 cand h-part
    pack_frags<<<256, 256, 0, stream>>>(Wg1, 1024, 0,   16, 64, Wg1xf);  // layer1 gate x-part
    pack_frags<<<256, 256, 0, stream>>>(Wg1, 1024, 512, 16, 64, Wg1hf);  // layer1 gate h-part
    pack_frags<<<128, 256, 0, stream>>>(Wc1,  512, 0,   16, 32, Wc1xf);  // layer1 cand x-part
    pack_frags<<<128, 256, 0, stream>>>(Wc1,  512, 512, 16, 32, Wc1hf);  // layer1 cand h-part
    // layer-0 input projections (K=200, fp32)
    gemm_bias<<<dim3(16, 79), 256, 0, stream>>>(xs, Wg0, bg0, Xg0, BT_, 1024, D0_, 1024);
    gemm_bias<<<dim3(8, 79), 256, 0, stream>>>(xs, Wc0, bc0, Xc0, BT_, 512, D0_, 512);
    // pass 1: layer-0 recurrence -> h0seq (bf16)
    rnn_pass<<<50, 512, 0, stream>>>(Xg0, Xc0, Wg0f, Wc0f, h0seq, nullptr);
    // layer-1 input projections from h0seq (MFMA, K=512)
    xproj_mfma<16><<<313, 256, 0, stream>>>(h0seq, Wg1xf, bg1, Xg1, BT_);
    xproj_mfma<8><<<313, 256, 0, stream>>>(h0seq, Wc1xf, bc1, Xc1, BT_);
    // pass 2: layer-1 recurrence -> h1o (fp32)
    rnn_pass<<<50, 512, 0, stream>>>(Xg1, Xc1, Wg1hf, Wc1hf, nullptr, h1o);
    // fused softmax GEMM + LSE partials + target pick
    lse_gemm<<<dim3(125, 79), 256, 0, stream>>>(h1o, sw, sb, tgt, ztb, parts, BT_);
    final_nll<<<40, 128, 0, stream>>>(parts, ztb, bsum);
    final_sum<<<1, 64, 0, stream>>>(bsum, out);
}

// Round 9
// 1943.233 us; speedup vs baseline: 3.0224x; 1.2787x over previous
//
#include <hip/hip_runtime.h>
#include <hip/hip_bf16.h>
#include <math.h>

// Problem constants
#define V_    8000
#define E_    150
#define LD_   50
#define H_    512
#define B_    100
#define T_    50
#define D0_   200   // E_+LD_
#define BT_   5000  // B_*T_
#define NV_   8000

typedef __attribute__((ext_vector_type(8))) short short8v;
typedef __attribute__((ext_vector_type(4))) float f32x4;

__device__ __forceinline__ float sigmoidf_(float x) { return 1.0f / (1.0f + expf(-x)); }
__device__ __forceinline__ unsigned short f2b(float x) {
    __hip_bfloat16 b = __float2bfloat16(x);
    return *(unsigned short*)&b;
}

// ---------------- row L2-normalize
__global__ __launch_bounds__(256) void norm_rows(const float* __restrict__ in,
                                                 float* __restrict__ out, int R, int C) {
    int row = blockIdx.x;
    if (row >= R) return;
    int tid = threadIdx.x;
    float v = (tid < C) ? in[(size_t)row * C + tid] : 0.f;
    __shared__ float red[256];
    red[tid] = v * v;
    __syncthreads();
    for (int s = 128; s > 0; s >>= 1) {
        if (tid < s) red[tid] += red[tid + s];
        __syncthreads();
    }
    float scale = rsqrtf(fmaxf(red[0], 1e-12f));
    if (tid < C) out[(size_t)row * C + tid] = v * scale;
}

// ---------------- build xs [m=t*100+b][D0] row-major
__global__ void build_xs(const int* __restrict__ inp, const int* __restrict__ langs,
                         const float* __restrict__ nemb, const float* __restrict__ nlang,
                         float* __restrict__ xs) {
    int idx = blockIdx.x * 256 + threadIdx.x;
    if (idx >= T_ * B_ * D0_) return;
    int t = idx / (B_ * D0_);
    int rem = idx % (B_ * D0_);
    int b = rem / D0_;
    int e = rem % D0_;
    float v;
    if (e < E_) v = nemb[(size_t)inp[b * T_ + t] * E_ + e];
    else        v = nlang[(size_t)langs[b] * LD_ + (e - E_)];
    xs[idx] = v;
}

// ---------------- fp32 tiled GEMM + bias: C[M,N] = A[M,K]@B[K,N](ldb) + bias
__global__ __launch_bounds__(256) void gemm_bias(const float* __restrict__ A,
                                                 const float* __restrict__ Bm,
                                                 const float* __restrict__ bias,
                                                 float* __restrict__ C,
                                                 int M, int N, int K, int ldb) {
    __shared__ __align__(16) float As[16][64];
    __shared__ __align__(16) float Bs[16][64];
    const int tid = threadIdx.x;
    const int tx = tid & 15, ty = tid >> 4;
    const int mBase = blockIdx.y * 64, nBase = blockIdx.x * 64;
    float acc[4][4] = {};
    for (int k0 = 0; k0 < K; k0 += 16) {
        int e = tid * 4;
#pragma unroll
        for (int q = 0; q < 4; ++q) {
            int ee = e + q;
            int r = ee >> 4, kk = ee & 15;
            int gr = mBase + r, gk = k0 + kk;
            As[kk][r] = (gr < M && gk < K) ? A[(size_t)gr * K + gk] : 0.f;
        }
        int bk = tid >> 4, bn = (tid & 15) * 4;
        int gk = k0 + bk;
        float4 bv = make_float4(0.f, 0.f, 0.f, 0.f);
        if (gk < K) bv = *(const float4*)(Bm + (size_t)gk * ldb + nBase + bn);
        *(float4*)&Bs[bk][bn] = bv;
        __syncthreads();
#pragma unroll
        for (int kk = 0; kk < 16; ++kk) {
            const float4 a4 = *(const float4*)&As[kk][ty * 4];
            const float4 b4 = *(const float4*)&Bs[kk][tx * 4];
            float a[4] = {a4.x, a4.y, a4.z, a4.w};
            float b[4] = {b4.x, b4.y, b4.z, b4.w};
#pragma unroll
            for (int i = 0; i < 4; ++i)
#pragma unroll
                for (int j = 0; j < 4; ++j) acc[i][j] += a[i] * b[j];
        }
        __syncthreads();
    }
#pragma unroll
    for (int i = 0; i < 4; ++i) {
        int gr = mBase + ty * 4 + i;
        if (gr < M) {
#pragma unroll
            for (int j = 0; j < 4; ++j) {
                int gc = nBase + tx * 4 + j;
                if (gc < N) C[(size_t)gr * N + gc] = acc[i][j] + bias[gc];
            }
        }
    }
}

// ---------------- pack fp32 weight [K][ldw] (rows k0off..) into bf16 MFMA B-frag layout:
// dst[((kt*NT + nt)*64 + lane)*8 + j] = bf16(W[k0off + kt*32 + (lane>>4)*8 + j][nt*16 + (lane&15)])
__global__ __launch_bounds__(256) void pack_frags(const float* __restrict__ W, int ldw,
                                                  int k0off, int KT, int NT,
                                                  unsigned short* __restrict__ dst) {
    int idx = blockIdx.x * 256 + threadIdx.x;
    if (idx >= KT * NT * 64) return;
    int lane = idx & 63;
    int tile = idx >> 6;
    int nt = tile % NT, kt = tile / NT;
    int n = nt * 16 + (lane & 15);
    int kb = k0off + kt * 32 + (lane >> 4) * 8;
    unsigned short o[8];
#pragma unroll
    for (int j = 0; j < 8; ++j) o[j] = f2b(W[(size_t)(kb + j) * ldw + n]);
    *(uint4*)(dst + (size_t)idx * 8) = *(const uint4*)o;
}

// ---------------- MFMA recurrence phase (proven simple loop, compiler-scheduled).
// K = 16*32 = 512. aoff = (lane&15)*520 + (lane>>4)*8.
template<int NTW>
__device__ __forceinline__ void mm_phase(const unsigned short* __restrict__ Wf, int NT,
                                         const unsigned short* a0,
                                         int w, int lane, int aoff, f32x4* acc) {
#pragma unroll 2
    for (int kt = 0; kt < 16; ++kt) {
        short8v af = *(const short8v*)(a0 + aoff + kt * 32);
        const unsigned short* wp = Wf + ((size_t)(kt * NT + w * NTW) * 64 + lane) * 8;
#pragma unroll
        for (int nt = 0; nt < NTW; ++nt) {
            short8v bf = *(const short8v*)(wp + (size_t)nt * 512);
            acc[nt] = __builtin_amdgcn_mfma_f32_16x16x32_bf16(af, bf, acc[nt], 0, 0, 0);
        }
    }
}

// ---------------- one-layer GRU pass: 50 blocks x 2 batch rows, 1024 threads (16 waves)
// gates = sigmoid(Xg[m] + h @ Wgf); h = u*h + (1-u)*tanh(Xc[m] + (r*h) @ Wcf)
// Weight set per step = 1.5 MB (L2-resident). Output: houtb (bf16 [m][512]).
__global__ __launch_bounds__(1024) void rnn_pass(
    const float* __restrict__ Xg, const float* __restrict__ Xc,
    const unsigned short* __restrict__ Wgf, const unsigned short* __restrict__ Wcf,
    unsigned short* __restrict__ houtb) {
    __shared__ __align__(16) unsigned short hb[16 * 520];
    __shared__ __align__(16) unsigned short rhb[16 * 520];
    __shared__ float hf[2 * 512], uf[2 * 512];
    const int tid = threadIdx.x;
    const int w = tid >> 6, lane = tid & 63;   // w in 0..15
    const int arow = lane & 15;
    const int aoff = arow * 520 + (lane >> 4) * 8;
    const int rb = blockIdx.x * 2;

    for (int i = tid; i < 16 * 520; i += 1024) { hb[i] = 0; rhb[i] = 0; }
    for (int i = tid; i < 2 * 512; i += 1024) hf[i] = 0.f;
    __syncthreads();

    for (int t = 0; t < T_; ++t) {
        const int m0 = t * 100 + rb, m1 = m0 + 1;
        {   // phase A: gates [N=1024, K=512]; wave w owns n-tiles w*4..w*4+3
            f32x4 acc[4];
#pragma unroll
            for (int nt = 0; nt < 4; ++nt) acc[nt] = (f32x4){0.f, 0.f, 0.f, 0.f};
            mm_phase<4>(Wgf, 64, hb, w, lane, aoff, acc);
            if (lane < 16) {
#pragma unroll
                for (int nt = 0; nt < 4; ++nt) {
                    int col = (w * 4 + nt) * 16 + arow;
                    float s0 = sigmoidf_(acc[nt][0] + Xg[(size_t)m0 * 1024 + col]);
                    float s1 = sigmoidf_(acc[nt][1] + Xg[(size_t)m1 * 1024 + col]);
                    if (col < 512) {
                        rhb[col]       = f2b(s0 * hf[col]);
                        rhb[520 + col] = f2b(s1 * hf[512 + col]);
                    } else {
                        uf[col - 512] = s0;
                        uf[col]       = s1;
                    }
                }
            }
        }
        __syncthreads();
        {   // phase B: candidate + h update [N=512, K=512]; wave w owns n-tiles w*2..w*2+1
            f32x4 acc[2];
#pragma unroll
            for (int nt = 0; nt < 2; ++nt) acc[nt] = (f32x4){0.f, 0.f, 0.f, 0.f};
            mm_phase<2>(Wcf, 32, rhb, w, lane, aoff, acc);
            if (lane < 16) {
#pragma unroll
                for (int nt = 0; nt < 2; ++nt) {
                    int col = (w * 2 + nt) * 16 + arow;
                    float c0 = tanhf(acc[nt][0] + Xc[(size_t)m0 * 512 + col]);
                    float c1 = tanhf(acc[nt][1] + Xc[(size_t)m1 * 512 + col]);
                    float uA = uf[col], uB = uf[512 + col];
                    float hA = uA * hf[col] + (1.f - uA) * c0;
                    float hB = uB * hf[512 + col] + (1.f - uB) * c1;
                    hf[col] = hA; hf[512 + col] = hB;
                    unsigned short bA = f2b(hA), bB = f2b(hB);
                    hb[col] = bA; hb[520 + col] = bB;
                    houtb[(size_t)m0 * 512 + col] = bA;
                    houtb[(size_t)m1 * 512 + col] = bB;
                }
            }
        }
        __syncthreads();
    }
}

// ---------------- batched MFMA x-projection GEMM: C[M][N] = Abf[M][512] @ Wf + bias
// One 16-row M-tile per block, 4 waves x NTW n-tiles. N = NTW*4*16.
template<int NTW>
__global__ __launch_bounds__(256) void xproj_mfma(const unsigned short* __restrict__ Abf,
                                                  const unsigned short* __restrict__ Wf,
                                                  const float* __restrict__ bias,
                                                  float* __restrict__ C, int M) {
    const int NT = NTW * 4;
    const int N = NT * 16;
    const int tid = threadIdx.x;
    const int w = tid >> 6, lane = tid & 63;
    const int arow = lane & 15, hi = lane >> 4;
    const int mbase = blockIdx.x * 16;
    int ga = mbase + arow; if (ga >= M) ga = M - 1;      // clamp reads; stores guarded
    const unsigned short* ap = Abf + (size_t)ga * 512 + hi * 8;
    f32x4 acc[NTW];
#pragma unroll
    for (int nt = 0; nt < NTW; ++nt) acc[nt] = (f32x4){0.f, 0.f, 0.f, 0.f};
#pragma unroll 2
    for (int kt = 0; kt < 16; ++kt) {
        short8v af = *(const short8v*)(ap + kt * 32);
        const unsigned short* wp = Wf + ((size_t)(kt * NT + w * NTW) * 64 + lane) * 8;
#pragma unroll
        for (int nt = 0; nt < NTW; ++nt) {
            short8v bf = *(const short8v*)(wp + (size_t)nt * 512);
            acc[nt] = __builtin_amdgcn_mfma_f32_16x16x32_bf16(af, bf, acc[nt], 0, 0, 0);
        }
    }
    // C layout: row = hi*4+q, col = tile*16 + arow
#pragma unroll
    for (int nt = 0; nt < NTW; ++nt) {
        int col = (w * NTW + nt) * 16 + arow;
        float bb = bias[col];
#pragma unroll
        for (int q = 0; q < 4; ++q) {
            int gm = mbase + hi * 4 + q;
            if (gm < M) C[(size_t)gm * N + col] = acc[nt][q] + bb;
        }
    }
}

// ---------------- MFMA fused softmax GEMM: logits tile (64 rows x 64 cols) via bf16 MFMA,
// in-register bias/target-pick/rowmax/sumexp (no LDS, no barriers).
// A = h1o bf16 [BT][512]; swf = sw packed B-frags (NT=500). grid (125, 79), 256 thr.
__global__ __launch_bounds__(256) void lse_mfma(const unsigned short* __restrict__ Abf,
                                                const unsigned short* __restrict__ swf,
                                                const float* __restrict__ sb,
                                                const int* __restrict__ tgt,
                                                float* __restrict__ zt,
                                                float* __restrict__ parts) {
    const int tid = threadIdx.x;
    const int w = tid >> 6, lane = tid & 63;
    const int arow = lane & 15, hi = lane >> 4;
    const int mbase = blockIdx.y * 64 + w * 16;          // wave-private 16-row M-tile
    const int ntg0 = blockIdx.x * 4;                     // 4 n-tiles = 64 cols
    int ga = mbase + arow; if (ga >= BT_) ga = BT_ - 1;  // clamp reads
    const unsigned short* ap = Abf + (size_t)ga * 512 + hi * 8;
    f32x4 acc[4];
#pragma unroll
    for (int nt = 0; nt < 4; ++nt) acc[nt] = (f32x4){0.f, 0.f, 0.f, 0.f};
#pragma unroll 2
    for (int kt = 0; kt < 16; ++kt) {
        short8v af = *(const short8v*)(ap + kt * 32);
        const unsigned short* wp = swf + ((size_t)(kt * 500 + ntg0) * 64 + lane) * 8;
#pragma unroll
        for (int nt = 0; nt < 4; ++nt) {
            short8v bf = *(const short8v*)(wp + (size_t)nt * 512);
            acc[nt] = __builtin_amdgcn_mfma_f32_16x16x32_bf16(af, bf, acc[nt], 0, 0, 0);
        }
    }
    // bias
#pragma unroll
    for (int nt = 0; nt < 4; ++nt) {
        float bb = sb[(ntg0 + nt) * 16 + arow];
#pragma unroll
        for (int q = 0; q < 4; ++q) acc[nt][q] += bb;
    }
    // target-logit pick: row gr -> tgt[(gr%100)*50 + gr/100]; col = (ntg0+nt)*16 + arow
#pragma unroll
    for (int q = 0; q < 4; ++q) {
        int gr = mbase + hi * 4 + q;
        if (gr < BT_) {
            int tg = tgt[(gr % 100) * 50 + gr / 100];
            int lt = tg - arow;
#pragma unroll
            for (int nt = 0; nt < 4; ++nt)
                if (lt == (ntg0 + nt) * 16) zt[gr] = acc[nt][q];
        }
    }
    // per-row (hi,q) max over nt and the 16 arow lanes
    float lm[4], ls[4];
#pragma unroll
    for (int q = 0; q < 4; ++q) {
        float m = fmaxf(fmaxf(acc[0][q], acc[1][q]), fmaxf(acc[2][q], acc[3][q]));
        lm[q] = m;
    }
#pragma unroll
    for (int mask = 1; mask < 16; mask <<= 1)
#pragma unroll
        for (int q = 0; q < 4; ++q) lm[q] = fmaxf(lm[q], __shfl_xor(lm[q], mask));
#pragma unroll
    for (int q = 0; q < 4; ++q) {
        float s = 0.f;
#pragma unroll
        for (int nt = 0; nt < 4; ++nt) s += expf(acc[nt][q] - lm[q]);
        ls[q] = s;
    }
#pragma unroll
    for (int mask = 1; mask < 16; mask <<= 1)
#pragma unroll
        for (int q = 0; q < 4; ++q) ls[q] += __shfl_xor(ls[q], mask);
    if (arow == 0) {
#pragma unroll
        for (int q = 0; q < 4; ++q) {
            int gr = mbase + hi * 4 + q;
            if (gr < BT_) {
                parts[(size_t)gr * 250 + blockIdx.x * 2 + 0] = lm[q];
                parts[(size_t)gr * 250 + blockIdx.x * 2 + 1] = ls[q];
            }
        }
    }
}

// ---------------- merge partials -> NLL -> block sums
__global__ __launch_bounds__(128) void final_nll(const float* __restrict__ parts,
                                                 const float* __restrict__ zt,
                                                 float* __restrict__ bsum) {
    int i = blockIdx.x * 128 + threadIdx.x;
    float nll = 0.f;
    if (i < BT_) {
        const float* p = parts + (size_t)i * 250;
        float M = p[0];
        for (int j = 1; j < 125; ++j) M = fmaxf(M, p[2 * j]);
        float S = 0.f;
        for (int j = 0; j < 125; ++j) S += p[2 * j + 1] * expf(p[2 * j] - M);
        nll = M + logf(S) - zt[i];
    }
    __shared__ float red[128];
    red[threadIdx.x] = nll;
    __syncthreads();
    for (int s = 64; s > 0; s >>= 1) {
        if (threadIdx.x < s) red[threadIdx.x] += red[threadIdx.x + s];
        __syncthreads();
    }
    if (threadIdx.x == 0) bsum[blockIdx.x] = red[0];
}

__global__ __launch_bounds__(64) void final_sum(const float* __restrict__ bsum,
                                                float* __restrict__ out) {
    int tid = threadIdx.x;
    float v = (tid < 40) ? bsum[tid] : 0.f;
    for (int off = 32; off > 0; off >>= 1) v += __shfl_down(v, off);
    if (tid == 0) out[0] = v / 5000.0f;
}

extern "C" void kernel_launch(void* const* d_in, const int* in_sizes, int n_in,
                              void* d_out, int out_size, void* d_ws, size_t ws_size,
                              hipStream_t stream) {
    const int*   inp   = (const int*)d_in[0];
    const int*   langs = (const int*)d_in[1];
    const int*   tgt   = (const int*)d_in[2];
    const float* emb   = (const float*)d_in[3];
    const float* lemb  = (const float*)d_in[4];
    const float* Wg0   = (const float*)d_in[5];
    const float* bg0   = (const float*)d_in[6];
    const float* Wc0   = (const float*)d_in[7];
    const float* bc0   = (const float*)d_in[8];
    const float* Wg1   = (const float*)d_in[9];
    const float* bg1   = (const float*)d_in[10];
    const float* Wc1   = (const float*)d_in[11];
    const float* bc1   = (const float*)d_in[12];
    const float* sw    = (const float*)d_in[13];
    const float* sb    = (const float*)d_in[14];
    float* out = (float*)d_out;

    // workspace layout (floats), max offset 11,160,512 floats = 44.6 MB
    float* w = (float*)d_ws;
    // region A [0 .. 1,200,000): nemb, later aliased by packed weight frags (2,359,296 u16)
    float* nemb  = w;
    unsigned short* Wg0f  = (unsigned short*)w;                //   524,288 u16
    unsigned short* Wc0f  = Wg0f + 524288;                     //   262,144
    unsigned short* Wg1xf = Wc0f + 262144;                     //   524,288
    unsigned short* Wg1hf = Wg1xf + 524288;                    //   524,288
    unsigned short* Wc1xf = Wg1hf + 524288;                    //   262,144
    unsigned short* Wc1hf = Wc1xf + 262144;                    //   262,144 (ends 2,359,296 u16)
    float* nlang = w + 1200000;             // 512
    float* xs    = w + 1200512;             // 1,000,000 (dead after Xg0/Xc0 gemms)
    // region B @2200512 (5.12M): Xg0 -> Xg1 (alias) -> swf (alias, after pass2)
    float* Xg0   = w + 2200512;
    float* Xg1   = w + 2200512;
    unsigned short* swf = (unsigned short*)(w + 2200512);      // 8,192,000 u16 = 4.096M fl
    // region C @7320512 (2.56M): Xc0 -> Xc1 (alias) -> parts/zt/bsum (alias, after pass2)
    float* Xc0   = w + 7320512;
    float* Xc1   = w + 7320512;
    float* parts = w + 7320512;             // 1,250,000
    float* ztb   = w + 7320512 + 1250000;   // 5,000
    float* bsum  = w + 7320512 + 1255000;   // 64
    // region D @9880512: h0seq bf16 (1.31M fl) -> h1o bf16 (alias, 1.28M fl)
    unsigned short* h0seq = (unsigned short*)(w + 9880512);    // 2,621,440 u16
    unsigned short* h1o   = (unsigned short*)(w + 9880512);    // 2,560,000 u16

    norm_rows<<<V_, 256, 0, stream>>>(emb, nemb, V_, E_);
    norm_rows<<<10, 256, 0, stream>>>(lemb, nlang, 10, LD_);
    build_xs<<<(T_ * B_ * D0_ + 255) / 256, 256, 0, stream>>>(inp, langs, nemb, nlang, xs);
    // pack GRU weight slices to bf16 frag layout (overwrites nemb; after build_xs)
    pack_frags<<<256, 256, 0, stream>>>(Wg0, 1024, D0_, 16, 64, Wg0f);   // layer0 gate h-part
    pack_frags<<<128, 256, 0, stream>>>(Wc0,  512, D0_, 16, 32, Wc0f);   // layer0 cand h-part
    pack_frags<<<256, 256, 0, stream>>>(Wg1, 1024, 0,   16, 64, Wg1xf);  // layer1 gate x-part
    pack_frags<<<256, 256, 0, stream>>>(Wg1, 1024, 512, 16, 64, Wg1hf);  // layer1 gate h-part
    pack_frags<<<128, 256, 0, stream>>>(Wc1,  512, 0,   16, 32, Wc1xf);  // layer1 cand x-part
    pack_frags<<<128, 256, 0, stream>>>(Wc1,  512, 512, 16, 32, Wc1hf);  // layer1 cand h-part
    // layer-0 input projections (K=200, fp32)
    gemm_bias<<<dim3(16, 79), 256, 0, stream>>>(xs, Wg0, bg0, Xg0, BT_, 1024, D0_, 1024);
    gemm_bias<<<dim3(8, 79), 256, 0, stream>>>(xs, Wc0, bc0, Xc0, BT_, 512, D0_, 512);
    // pass 1: layer-0 recurrence -> h0seq (bf16)
    rnn_pass<<<50, 1024, 0, stream>>>(Xg0, Xc0, Wg0f, Wc0f, h0seq);
    // layer-1 input projections from h0seq (MFMA, K=512)
    xproj_mfma<16><<<313, 256, 0, stream>>>(h0seq, Wg1xf, bg1, Xg1, BT_);
    xproj_mfma<8><<<313, 256, 0, stream>>>(h0seq, Wc1xf, bc1, Xc1, BT_);
    // pass 2: layer-1 recurrence -> h1o (bf16)
    rnn_pass<<<50, 1024, 0, stream>>>(Xg1, Xc1, Wg1hf, Wc1hf, h1o);
    // pack softmax weights to bf16 frags (over dead Xg1) after pass 2
    pack_frags<<<2000, 256, 0, stream>>>(sw, NV_, 0, 16, 500, swf);
    // fused MFMA softmax GEMM + LSE partials + target pick (parts over dead Xc1)
    lse_mfma<<<dim3(125, 79), 256, 0, stream>>>(h1o, swf, sb, tgt, ztb, parts);
    final_nll<<<40, 128, 0, stream>>>(parts, ztb, bsum);
    final_sum<<<1, 64, 0, stream>>>(bsum, out);
}